// Round 5
// baseline (319.532 us; speedup 1.0000x reference)
//
#include <hip/hip_runtime.h>

#define N_NODES 100000
#define N_EDGES 1600000
#define D 64

#define NSEG 8                         // dst-space segments (XCD-local write windows)
#define SEG_NODES (N_NODES / NSEG)     // 12500
#define FILL_WPS 128                   // workgroups per segment
#define FILL_CH ((N_EDGES + FILL_WPS - 1) / FILL_WPS)  // 12500 edges per chunk

// manual bf16 round-to-nearest-even (avoid header struct-layout quirks)
static __device__ __forceinline__ unsigned short f2bf(float f) {
    unsigned u = __float_as_uint(f);
    u += 0x7FFFu + ((u >> 16) & 1u);
    return (unsigned short)(u >> 16);
}
static __device__ __forceinline__ float bf2f(unsigned short h) {
    return __uint_as_float((unsigned)h << 16);
}

// ---------------- GEMM: support(bf16) = X @ W ----------------
__global__ __launch_bounds__(256) void gcn_gemm(const float* __restrict__ x,
                                                const float* __restrict__ w,
                                                unsigned short* __restrict__ support) {
    __shared__ float4 wsh[64 * 16];
    int tid = threadIdx.x;
    const float4* w4 = (const float4*)w;
    for (int i = tid; i < 64 * 16; i += 256) wsh[i] = w4[i];
    __syncthreads();

    int idx = blockIdx.x * 256 + tid;
    int rowpair = idx >> 4;
    int c4 = idx & 15;
    long r0 = (long)rowpair * 2;
    const float4* xr0 = (const float4*)(x + r0 * D);
    const float4* xr1 = (const float4*)(x + (r0 + 1) * D);

    float4 a0 = make_float4(0.f, 0.f, 0.f, 0.f);
    float4 a1 = make_float4(0.f, 0.f, 0.f, 0.f);
    #pragma unroll 4
    for (int k4 = 0; k4 < 16; ++k4) {
        float4 xv0 = xr0[k4];
        float4 xv1 = xr1[k4];
        float4 w0 = wsh[(4 * k4 + 0) * 16 + c4];
        float4 w1 = wsh[(4 * k4 + 1) * 16 + c4];
        float4 w2 = wsh[(4 * k4 + 2) * 16 + c4];
        float4 w3 = wsh[(4 * k4 + 3) * 16 + c4];
        a0 += w0 * xv0.x + w1 * xv0.y + w2 * xv0.z + w3 * xv0.w;
        a1 += w0 * xv1.x + w1 * xv1.y + w2 * xv1.z + w3 * xv1.w;
    }
    ushort4* s4 = (ushort4*)support;
    ushort4 p0 = make_ushort4(f2bf(a0.x), f2bf(a0.y), f2bf(a0.z), f2bf(a0.w));
    ushort4 p1 = make_ushort4(f2bf(a1.x), f2bf(a1.y), f2bf(a1.z), f2bf(a1.w));
    s4[r0 * 16 + c4] = p0;
    s4[(r0 + 1) * 16 + c4] = p1;
}

// ---------------- binning: single-pass count ----------------
__global__ __launch_bounds__(256) void gcn_count(const int* __restrict__ dst,
                                                 int* __restrict__ counts) {
    int e = blockIdx.x * 256 + threadIdx.x;
    if (e < N_EDGES) {
        int d = __builtin_nontemporal_load(&dst[e]);
        atomicAdd(&counts[d], 1);
    }
}

#define SCAN_B 1024
__global__ __launch_bounds__(256) void gcn_scan1(const int* __restrict__ counts,
                                                 int* __restrict__ offs,
                                                 int* __restrict__ bsums) {
    __shared__ int sh[256];
    int tid = threadIdx.x;
    int base = blockIdx.x * SCAN_B + tid * 4;
    int v0 = (base + 0 < N_NODES) ? counts[base + 0] : 0;
    int v1 = (base + 1 < N_NODES) ? counts[base + 1] : 0;
    int v2 = (base + 2 < N_NODES) ? counts[base + 2] : 0;
    int v3 = (base + 3 < N_NODES) ? counts[base + 3] : 0;
    int local = v0 + v1 + v2 + v3;
    sh[tid] = local;
    __syncthreads();
    for (int off = 1; off < 256; off <<= 1) {
        int t = 0;
        if (tid >= off) t = sh[tid - off];
        __syncthreads();
        if (tid >= off) sh[tid] += t;
        __syncthreads();
    }
    int excl = sh[tid] - local;
    if (base + 0 < N_NODES) offs[base + 0] = excl;
    if (base + 1 < N_NODES) offs[base + 1] = excl + v0;
    if (base + 2 < N_NODES) offs[base + 2] = excl + v0 + v1;
    if (base + 3 < N_NODES) offs[base + 3] = excl + v0 + v1 + v2;
    if (tid == 255) bsums[blockIdx.x] = sh[255];
}

#define NB1 98  // ceil(100000/1024)
__global__ __launch_bounds__(128) void gcn_scan2(int* __restrict__ bsums) {
    __shared__ int sh[128];
    int tid = threadIdx.x;
    int orig = (tid < NB1) ? bsums[tid] : 0;
    sh[tid] = orig;
    __syncthreads();
    for (int off = 1; off < 128; off <<= 1) {
        int t = 0;
        if (tid >= off) t = sh[tid - off];
        __syncthreads();
        if (tid >= off) sh[tid] += t;
        __syncthreads();
    }
    if (tid < NB1) bsums[tid] = sh[tid] - orig;  // exclusive
}

__global__ __launch_bounds__(256) void gcn_scan3(int* __restrict__ offs,
                                                 const int* __restrict__ bsums,
                                                 int* __restrict__ cursor) {
    int i = blockIdx.x * 256 + threadIdx.x;
    if (i < N_NODES) {
        int o = offs[i] + bsums[i >> 10];
        offs[i] = o;
        cursor[i] = o;
    }
}

// fill: NT loads for all streaming reads so the scatter write-front stays
// L2-resident; normal (cacheable) stores so partial lines can merge in L2.
__global__ __launch_bounds__(256) void gcn_fill_seg(const int* __restrict__ src,
                                                    const int* __restrict__ dst,
                                                    const float* __restrict__ adj,
                                                    int* __restrict__ cursor,
                                                    int2* __restrict__ edges) {
    int seg = blockIdx.x & (NSEG - 1);
    int w = blockIdx.x >> 3;
    int lo = seg * SEG_NODES, hi = lo + SEG_NODES;
    int e0 = w * FILL_CH;
    int e1 = min(e0 + FILL_CH, N_EDGES);
    for (int e = e0 + (int)threadIdx.x; e < e1; e += 256) {
        int d = __builtin_nontemporal_load(&dst[e]);
        if (d >= lo && d < hi) {
            int s = __builtin_nontemporal_load(&src[e]);
            float a = __builtin_nontemporal_load(&adj[e]);
            int pos = atomicAdd(&cursor[d], 1);
            edges[pos] = make_int2(s, __float_as_int(a));
        }
    }
}

// ---------------- gather: one wave per node, LDS edge staging, ILP-8, bf16 support ----------------
__global__ __launch_bounds__(256) void gcn_gather(const unsigned short* __restrict__ support,
                                                  const long long* __restrict__ edges,
                                                  const int* __restrict__ offs,
                                                  const int* __restrict__ counts,
                                                  const float* __restrict__ bias,
                                                  float* __restrict__ out) {
    __shared__ int2 eL[4][64];
    int tid = threadIdx.x;
    int wv = tid >> 6, lane = tid & 63;
    int n = blockIdx.x * 4 + wv;
    int start = offs[n];
    int cnt = counts[n];
    float acc = bias[lane];

    for (int c = 0; c < cnt; c += 64) {
        int rem = min(64, cnt - c);
        if (lane < rem) {
            long long p = __builtin_nontemporal_load(&edges[start + c + lane]);
            eL[wv][lane] = make_int2((int)(p & 0xFFFFFFFFll), (int)(p >> 32));
        }
        __builtin_amdgcn_wave_barrier();
        int j = 0;
        for (; j + 8 <= rem; j += 8) {
            int2 e0 = eL[wv][j + 0], e1 = eL[wv][j + 1];
            int2 e2 = eL[wv][j + 2], e3 = eL[wv][j + 3];
            int2 e4 = eL[wv][j + 4], e5 = eL[wv][j + 5];
            int2 e6 = eL[wv][j + 6], e7 = eL[wv][j + 7];
            float v0 = bf2f(support[(long)e0.x * D + lane]);
            float v1 = bf2f(support[(long)e1.x * D + lane]);
            float v2 = bf2f(support[(long)e2.x * D + lane]);
            float v3 = bf2f(support[(long)e3.x * D + lane]);
            float v4 = bf2f(support[(long)e4.x * D + lane]);
            float v5 = bf2f(support[(long)e5.x * D + lane]);
            float v6 = bf2f(support[(long)e6.x * D + lane]);
            float v7 = bf2f(support[(long)e7.x * D + lane]);
            acc += __int_as_float(e0.y) * v0;
            acc += __int_as_float(e1.y) * v1;
            acc += __int_as_float(e2.y) * v2;
            acc += __int_as_float(e3.y) * v3;
            acc += __int_as_float(e4.y) * v4;
            acc += __int_as_float(e5.y) * v5;
            acc += __int_as_float(e6.y) * v6;
            acc += __int_as_float(e7.y) * v7;
        }
        for (; j < rem; ++j) {
            int2 e0 = eL[wv][j];
            acc += __int_as_float(e0.y) * bf2f(support[(long)e0.x * D + lane]);
        }
        __builtin_amdgcn_wave_barrier();
    }
    __builtin_nontemporal_store(acc, &out[(long)n * D + lane]);
}

extern "C" void kernel_launch(void* const* d_in, const int* in_sizes, int n_in,
                              void* d_out, int out_size, void* d_ws, size_t ws_size,
                              hipStream_t stream) {
    const float* x      = (const float*)d_in[0];
    const float* weight = (const float*)d_in[1];
    const float* bias   = (const float*)d_in[2];
    const float* adj    = (const float*)d_in[3];
    const int*   src    = (const int*)d_in[4];
    const int*   dst    = (const int*)d_in[5];
    float* out = (float*)d_out;

    unsigned short* support = (unsigned short*)d_ws;       // 12,800,000 B (bf16)
    int2*  edges   = (int2*)(support + N_NODES * D);       // 12,800,000 B
    int*   counts  = (int*)(edges + N_EDGES);              // 400,000 B
    int*   offs    = counts + N_NODES;                     // 400,000 B
    int*   cursor  = offs + N_NODES;                       // 400,000 B
    int*   bsums   = cursor + N_NODES;                     // 512 B

    hipLaunchKernelGGL(gcn_gemm, dim3(N_NODES * 16 / 2 / 256), dim3(256), 0, stream,
                       x, weight, support);
    hipMemsetAsync(counts, 0, N_NODES * sizeof(int), stream);
    hipLaunchKernelGGL(gcn_count, dim3((N_EDGES + 255) / 256), dim3(256), 0, stream,
                       dst, counts);
    hipLaunchKernelGGL(gcn_scan1, dim3(NB1), dim3(256), 0, stream, counts, offs, bsums);
    hipLaunchKernelGGL(gcn_scan2, dim3(1), dim3(128), 0, stream, bsums);
    hipLaunchKernelGGL(gcn_scan3, dim3((N_NODES + 255) / 256), dim3(256), 0, stream,
                       offs, bsums, cursor);
    hipLaunchKernelGGL(gcn_fill_seg, dim3(NSEG * FILL_WPS), dim3(256), 0, stream,
                       src, dst, adj, cursor, edges);
    hipLaunchKernelGGL(gcn_gather, dim3(N_NODES / 4), dim3(256), 0, stream,
                       support, (const long long*)edges, offs, counts, bias, out);
}